// Round 1
// baseline (430.163 us; speedup 1.0000x reference)
//
#include <hip/hip_runtime.h>
#include <cstdint>
#include <cstddef>

#define CH 64
#define NP 65536          // F*S
#define NPB 1024          // 64-pos tiles per batch
constexpr float EPS_LN = 1e-5f;

using f32x4  = __attribute__((ext_vector_type(4))) float;
using bf16x8 = __attribute__((ext_vector_type(8))) short;

__device__ __forceinline__ short f2bf(float f){
  union { float f; uint32_t u; } v; v.f = f;
  uint32_t r = v.u + 0x7FFFu + ((v.u >> 16) & 1u);
  return (short)(r >> 16);
}
__device__ __forceinline__ float bf2f(short s){
  union { uint32_t u; float f; } v; v.u = ((uint32_t)(uint16_t)s) << 16;
  return v.f;
}
__device__ __forceinline__ float sigmoidf_(float x){ return 1.f/(1.f+__expf(-x)); }

// ---------------- prep: x stats partials + bf16 weight conversion ----------------
__global__ __launch_bounds__(256) void k_prep(
    const float* __restrict__ x,
    const float* __restrict__ w1, const float* __restrict__ w2,
    const float* __restrict__ w3, const float* __restrict__ w4,
    float* __restrict__ xstat, short* __restrict__ wbf)
{
  int blk = blockIdx.x, tid = threadIdx.x;
  if (blk < 256) {
    int b = blk >> 6, chunk = blk & 63;
    const float* base = x + (size_t)b*CH*NP + (size_t)chunk*65536;
    float s = 0.f, s2 = 0.f;
    for (int i = tid*4; i < 65536; i += 1024) {
      f32x4 v = *(const f32x4*)(base + i);
      s  += v.x + v.y + v.z + v.w;
      s2 += v.x*v.x + v.y*v.y + v.z*v.z + v.w*v.w;
    }
    for (int d=1; d<64; d<<=1){ s += __shfl_xor(s,d,64); s2 += __shfl_xor(s2,d,64); }
    __shared__ float ls[8];
    int wv = tid>>6;
    if ((tid&63)==0){ ls[wv]=s; ls[4+wv]=s2; }
    __syncthreads();
    if (tid==0){
      xstat[blk*2]   = ls[0]+ls[1]+ls[2]+ls[3];
      xstat[blk*2+1] = ls[4]+ls[5]+ls[6]+ls[7];
    }
  } else {
    int wblk = blk - 256;  // 24 blocks x 1024 elems
    const float* src; short* dst; int off;
    if (wblk < 8)       { src = w1; dst = wbf;         off = wblk*1024; }
    else if (wblk < 12) { src = w2; dst = wbf + 8192;  off = (wblk-8)*1024; }
    else if (wblk < 20) { src = w3; dst = wbf + 12288; off = (wblk-12)*1024; }
    else                { src = w4; dst = wbf + 20480; off = (wblk-20)*1024; }
    for (int i = tid; i < 1024; i += 256) dst[off+i] = f2bf(src[off+i]);
  }
}

__global__ void k_fin1(const float* __restrict__ xstat, float* __restrict__ stats1){
  int t = threadIdx.x;
  if (t < 4){
    float s=0.f, s2=0.f;
    for (int i=0;i<64;i++){ s += xstat[(t*64+i)*2]; s2 += xstat[(t*64+i)*2+1]; }
    float m = s * (1.f/4194304.f);
    float v = s2 * (1.f/4194304.f) - m*m;
    stats1[t] = m; stats1[4+t] = rsqrtf(v + EPS_LN);
  }
}

// ---------------- branch1: LN1 + GEMM w1 + dw affine + GLU -> hglu(bf16) + p partials ----------------
__global__ __launch_bounds__(256) void k_branch1(
    const float* __restrict__ x, const float* __restrict__ lnw, const float* __restrict__ lnb,
    const short* __restrict__ w1bf, const float* __restrict__ b1,
    const float* __restrict__ dww, const float* __restrict__ dwb,
    const float* __restrict__ stats1, short* __restrict__ hglu, float* __restrict__ ppart)
{
  int b = blockIdx.x >> 10;
  int tile = blockIdx.x & (NPB-1);
  int tid = threadIdx.x;
  int wv = tid >> 6, lane = tid & 63, l = lane & 15, q = lane >> 4;
  int pos = tile*64 + wv*16 + l;
  float mean = stats1[b], rstd = stats1[4+b];
  const float* xb = x + (size_t)b*CH*NP;

  bf16x8 bfrag[2];
  #pragma unroll
  for (int ks=0; ks<2; ks++){
    #pragma unroll
    for (int j=0;j<8;j++){
      int c = ks*32 + q*8 + j;
      size_t idx = (size_t)c*NP + pos;
      float xn = (xb[idx] - mean)*rstd*lnw[idx] + lnb[idx];
      bfrag[ks][j] = f2bf(xn);
    }
  }
  f32x4 acc[8];
  #pragma unroll
  for (int mt=0; mt<8; mt++){
    f32x4 a = {0.f,0.f,0.f,0.f};
    #pragma unroll
    for (int ks=0; ks<2; ks++){
      bf16x8 af = *(const bf16x8*)(w1bf + ((mt*16 + l)*CH + ks*32 + q*8));
      a = __builtin_amdgcn_mfma_f32_16x16x32_bf16(af, bfrag[ks], a, 0, 0, 0);
    }
    acc[mt] = a;
  }
  short* hb = hglu + (size_t)b*CH*NP;
  float hv[16];
  #pragma unroll
  for (int mt=0; mt<4; mt++){
    #pragma unroll
    for (int r=0; r<4; r++){
      int oa = mt*16 + q*4 + r, og = oa + 64;
      float av = (acc[mt][r]   + b1[oa]) * dww[oa] + dwb[oa];
      float gv = (acc[mt+4][r] + b1[og]) * dww[og] + dwb[og];
      float h = av * sigmoidf_(gv);
      hv[mt*4+r] = h;
      hb[(size_t)oa*NP + pos] = f2bf(h);
    }
  }
  // channel pooling partials: sum over the wave's 16 positions, then across waves
  __shared__ float pacc[4][64];
  #pragma unroll
  for (int i=0;i<16;i++){
    float v = hv[i];
    v += __shfl_xor(v, 1, 64);
    v += __shfl_xor(v, 2, 64);
    v += __shfl_xor(v, 4, 64);
    v += __shfl_xor(v, 8, 64);
    if (l==0){ int mt = i>>2, r = i&3; pacc[wv][mt*16 + q*4 + r] = v; }
  }
  __syncthreads();
  if (tid < 64){
    float s = pacc[0][tid]+pacc[1][tid]+pacc[2][tid]+pacc[3][tid];
    ppart[((size_t)b*NPB + tile)*64 + tid] = s;
  }
}

// ---------------- channel attention MLP ----------------
__global__ __launch_bounds__(256) void k_attn(
    const float* __restrict__ ppart,
    const float* __restrict__ aw1, const float* __restrict__ ab1,
    const float* __restrict__ aw2, const float* __restrict__ ab2,
    float* __restrict__ sout)
{
  int b = blockIdx.x, t = threadIdx.x;
  int c = t & 63, seg = t >> 6;
  const float* pb = ppart + (size_t)b*NPB*64;
  float s = 0.f;
  for (int i = seg; i < NPB; i += 4) s += pb[i*64 + c];
  __shared__ float pl[4][64];
  pl[seg][c] = s;
  __syncthreads();
  __shared__ float parr[64], t1a[64];
  if (t < 64) parr[t] = (pl[0][t]+pl[1][t]+pl[2][t]+pl[3][t]) * (1.f/65536.f);
  __syncthreads();
  if (t < 64){
    float acc = ab1[t];
    for (int k=0;k<64;k++) acc += aw1[t*64+k]*parr[k];
    t1a[t] = fmaxf(acc, 0.f);
  }
  __syncthreads();
  if (t < 64){
    float acc = ab2[t];
    for (int k=0;k<64;k++) acc += aw2[t*64+k]*t1a[k];
    sout[b*64 + t] = sigmoidf_(acc);
  }
}

// ---------------- mid: h*s -> GEMM w2 + b2 + x -> y (d_out) + y stats partials ----------------
__global__ __launch_bounds__(256) void k_mid(
    const short* __restrict__ hglu, const float* __restrict__ sv,
    const short* __restrict__ w2bf, const float* __restrict__ b2,
    const float* __restrict__ x, float* __restrict__ y, float* __restrict__ ystat)
{
  int b = blockIdx.x >> 10;
  int tile = blockIdx.x & (NPB-1);
  int tid = threadIdx.x;
  int wv = tid>>6, lane = tid&63, l = lane&15, q = lane>>4;
  int pos = tile*64 + wv*16 + l;
  const short* hb = hglu + (size_t)b*CH*NP;
  const float* xb = x + (size_t)b*CH*NP;
  float* yb = y + (size_t)b*CH*NP;

  bf16x8 bfrag[2];
  #pragma unroll
  for (int ks=0; ks<2; ks++){
    #pragma unroll
    for (int j=0;j<8;j++){
      int c = ks*32 + q*8 + j;
      float hvv = bf2f(hb[(size_t)c*NP + pos]) * sv[b*64 + c];
      bfrag[ks][j] = f2bf(hvv);
    }
  }
  f32x4 acc[4];
  #pragma unroll
  for (int mt=0; mt<4; mt++){
    f32x4 a = {0.f,0.f,0.f,0.f};
    #pragma unroll
    for (int ks=0; ks<2; ks++){
      bf16x8 af = *(const bf16x8*)(w2bf + ((mt*16+l)*CH + ks*32 + q*8));
      a = __builtin_amdgcn_mfma_f32_16x16x32_bf16(af, bfrag[ks], a, 0, 0, 0);
    }
    acc[mt] = a;
  }
  float s1 = 0.f, s2 = 0.f;
  #pragma unroll
  for (int mt=0; mt<4; mt++){
    #pragma unroll
    for (int r=0;r<4;r++){
      int o = mt*16 + q*4 + r;
      float yv = acc[mt][r] + b2[o] + xb[(size_t)o*NP + pos];
      yb[(size_t)o*NP + pos] = yv;
      s1 += yv; s2 += yv*yv;
    }
  }
  for (int d=1; d<64; d<<=1){ s1 += __shfl_xor(s1,d,64); s2 += __shfl_xor(s2,d,64); }
  __shared__ float red[8];
  if (lane==0){ red[wv]=s1; red[4+wv]=s2; }
  __syncthreads();
  if (tid==0){
    ystat[(size_t)blockIdx.x*2]   = red[0]+red[1]+red[2]+red[3];
    ystat[(size_t)blockIdx.x*2+1] = red[4]+red[5]+red[6]+red[7];
  }
}

__global__ void k_fin2(const float* __restrict__ ystat, float* __restrict__ stats2){
  int t = threadIdx.x;           // 256
  int b = t >> 6, i0 = t & 63;
  float s=0.f, s2=0.f;
  for (int i=i0; i<NPB; i+=64){
    s  += ystat[((size_t)b*NPB+i)*2];
    s2 += ystat[((size_t)b*NPB+i)*2+1];
  }
  __shared__ float ls[4][64], l2[4][64];
  ls[b][i0]=s; l2[b][i0]=s2;
  __syncthreads();
  if (t < 4){
    float ts=0.f, t2=0.f;
    for (int i=0;i<64;i++){ ts+=ls[t][i]; t2+=l2[t][i]; }
    float m = ts*(1.f/4194304.f);
    float v = t2*(1.f/4194304.f) - m*m;
    stats2[t]=m; stats2[4+t]=rsqrtf(v+EPS_LN);
  }
}

// ---------------- branch2: LN2 + GEMM w3 + GLU + GEMM w4 + residual (in-place over y) ----------------
__global__ __launch_bounds__(256) void k_branch2(
    float* yio, const float* __restrict__ lnw, const float* __restrict__ lnb,
    const short* __restrict__ w3bf, const float* __restrict__ b3,
    const short* __restrict__ w4bf, const float* __restrict__ b4,
    const float* __restrict__ stats2)
{
  int b = blockIdx.x >> 10;
  int tile = blockIdx.x & (NPB-1);
  int tid = threadIdx.x;
  int wv = tid>>6, lane=tid&63, l=lane&15, q=lane>>4;
  int pos = tile*64 + wv*16 + l;
  float mean = stats2[b], rstd = stats2[4+b];
  float* yb = yio + (size_t)b*CH*NP;

  bf16x8 bfrag[2];
  #pragma unroll
  for (int ks=0;ks<2;ks++){
    #pragma unroll
    for (int j=0;j<8;j++){
      int c = ks*32+q*8+j;
      size_t idx = (size_t)c*NP + pos;
      float yn = (yb[idx]-mean)*rstd*lnw[idx] + lnb[idx];
      bfrag[ks][j] = f2bf(yn);
    }
  }
  float yres[16];
  #pragma unroll
  for (int mt=0;mt<4;mt++)
    #pragma unroll
    for (int r=0;r<4;r++)
      yres[mt*4+r] = yb[(size_t)(mt*16+q*4+r)*NP + pos];

  f32x4 acc[8];
  #pragma unroll
  for (int mt=0; mt<8; mt++){
    f32x4 a = {0.f,0.f,0.f,0.f};
    #pragma unroll
    for (int ks=0; ks<2; ks++){
      bf16x8 af = *(const bf16x8*)(w3bf + ((mt*16 + l)*CH + ks*32 + q*8));
      a = __builtin_amdgcn_mfma_f32_16x16x32_bf16(af, bfrag[ks], a, 0, 0, 0);
    }
    acc[mt] = a;
  }
  // GLU -> LDS transpose (pad row to 72 bf16: <=2-way bank aliasing, keeps 16B alignment)
  __shared__ __align__(16) short tr[4][16*72];
  #pragma unroll
  for (int mt=0;mt<4;mt++){
    #pragma unroll
    for (int r=0;r<4;r++){
      int c = mt*16 + q*4 + r;
      float av = acc[mt][r]   + b3[c];
      float gv = acc[mt+4][r] + b3[c+64];
      tr[wv][l*72 + c] = f2bf(av * sigmoidf_(gv));
    }
  }
  __syncthreads();
  bf16x8 pfrag[2];
  pfrag[0] = *(const bf16x8*)(&tr[wv][l*72 + q*8]);
  pfrag[1] = *(const bf16x8*)(&tr[wv][l*72 + 32 + q*8]);

  f32x4 acc2[4];
  #pragma unroll
  for (int mt=0; mt<4; mt++){
    f32x4 a = {0.f,0.f,0.f,0.f};
    #pragma unroll
    for (int ks=0; ks<2; ks++){
      bf16x8 af = *(const bf16x8*)(w4bf + ((mt*16+l)*CH + ks*32 + q*8));
      a = __builtin_amdgcn_mfma_f32_16x16x32_bf16(af, pfrag[ks], a, 0, 0, 0);
    }
    acc2[mt] = a;
  }
  #pragma unroll
  for (int mt=0; mt<4; mt++){
    #pragma unroll
    for (int r=0;r<4;r++){
      int o = mt*16 + q*4 + r;
      yb[(size_t)o*NP + pos] = acc2[mt][r] + b4[o] + yres[mt*4+r];
    }
  }
}

extern "C" void kernel_launch(void* const* d_in, const int* in_sizes, int n_in,
                              void* d_out, int out_size, void* d_ws, size_t ws_size,
                              hipStream_t stream){
  const float* x    = (const float*)d_in[0];
  const float* ln1w = (const float*)d_in[1];
  const float* ln1b = (const float*)d_in[2];
  const float* ln2w = (const float*)d_in[3];
  const float* ln2b = (const float*)d_in[4];
  const float* w1   = (const float*)d_in[5];
  const float* b1   = (const float*)d_in[6];
  const float* dww  = (const float*)d_in[7];
  const float* dwb  = (const float*)d_in[8];
  const float* aw1  = (const float*)d_in[9];
  const float* ab1  = (const float*)d_in[10];
  const float* aw2  = (const float*)d_in[11];
  const float* ab2  = (const float*)d_in[12];
  const float* w2   = (const float*)d_in[13];
  const float* b2   = (const float*)d_in[14];
  const float* w3   = (const float*)d_in[15];
  const float* b3   = (const float*)d_in[16];
  const float* w4   = (const float*)d_in[17];
  const float* b4   = (const float*)d_in[18];
  float* out = (float*)d_out;
  float* ws  = (float*)d_ws;

  // ws layout (float offsets): all regions fully written each call (no memset needed)
  float* xstat  = ws;                    // 512
  float* stats1 = ws + 1024;             // 8
  float* ystat  = ws + 2048;             // 8192
  float* stats2 = ws + 10496;            // 8
  float* sbuf   = ws + 11520;            // 256
  short* wbf    = (short*)(ws + 12288);  // 24576 bf16: w1|w2|w3|w4
  float* ppart  = ws + 24576;            // 262144
  short* hglu   = (short*)(ws + 286720); // 16777216 bf16 (32 MB); total ws ~34.7 MB

  hipLaunchKernelGGL(k_prep,    dim3(280),  dim3(256), 0, stream, x, w1, w2, w3, w4, xstat, wbf);
  hipLaunchKernelGGL(k_fin1,    dim3(1),    dim3(64),  0, stream, xstat, stats1);
  hipLaunchKernelGGL(k_branch1, dim3(4096), dim3(256), 0, stream, x, ln1w, ln1b, wbf, b1, dww, dwb, stats1, hglu, ppart);
  hipLaunchKernelGGL(k_attn,    dim3(4),    dim3(256), 0, stream, ppart, aw1, ab1, aw2, ab2, sbuf);
  hipLaunchKernelGGL(k_mid,     dim3(4096), dim3(256), 0, stream, hglu, sbuf, wbf + 8192, b2, x, out, ystat);
  hipLaunchKernelGGL(k_fin2,    dim3(1),    dim3(256), 0, stream, ystat, stats2);
  hipLaunchKernelGGL(k_branch2, dim3(4096), dim3(256), 0, stream, out, ln2w, ln2b, wbf + 12288, b3, wbf + 20480, b4, stats2);
}

// Round 2
// 412.830 us; speedup vs baseline: 1.0420x; 1.0420x over previous
//
#include <hip/hip_runtime.h>
#include <cstdint>
#include <cstddef>

#define CH 64
#define NP 65536          // F*S
#define NPB 1024          // 64-pos tiles per batch
constexpr float EPS_LN = 1e-5f;

using f32x4  = __attribute__((ext_vector_type(4))) float;
using bf16x8 = __attribute__((ext_vector_type(8))) short;
using s16x4  = __attribute__((ext_vector_type(4))) short;

__device__ __forceinline__ short f2bf(float f){
  union { float f; uint32_t u; } v; v.f = f;
  uint32_t r = v.u + 0x7FFFu + ((v.u >> 16) & 1u);
  return (short)(r >> 16);
}
__device__ __forceinline__ float bf2f(short s){
  union { uint32_t u; float f; } v; v.u = ((uint32_t)(uint16_t)s) << 16;
  return v.f;
}
__device__ __forceinline__ float sigmoidf_(float x){ return 1.f/(1.f+__expf(-x)); }

// ---------------- prep: x stats partials (1024 blks) + bf16 weight conversion (24 blks) ----------------
__global__ __launch_bounds__(256) void k_prep(
    const float* __restrict__ x,
    const float* __restrict__ w1, const float* __restrict__ w2,
    const float* __restrict__ w3, const float* __restrict__ w4,
    float* __restrict__ xstat, short* __restrict__ wbf)
{
  int blk = blockIdx.x, tid = threadIdx.x;
  if (blk < 1024) {
    int b = blk >> 8, chunk = blk & 255;
    const float* base = x + (size_t)b*CH*NP + (size_t)chunk*16384;
    float s = 0.f, s2 = 0.f;
    for (int i = tid*4; i < 16384; i += 1024) {
      f32x4 v = *(const f32x4*)(base + i);
      s  += v.x + v.y + v.z + v.w;
      s2 += v.x*v.x + v.y*v.y + v.z*v.z + v.w*v.w;
    }
    for (int d=1; d<64; d<<=1){ s += __shfl_xor(s,d,64); s2 += __shfl_xor(s2,d,64); }
    __shared__ float ls[8];
    int wv = tid>>6;
    if ((tid&63)==0){ ls[wv]=s; ls[4+wv]=s2; }
    __syncthreads();
    if (tid==0){
      xstat[blk*2]   = ls[0]+ls[1]+ls[2]+ls[3];
      xstat[blk*2+1] = ls[4]+ls[5]+ls[6]+ls[7];
    }
  } else {
    int wblk = blk - 1024;  // 24 blocks x 1024 elems
    const float* src; short* dst; int off;
    if (wblk < 8)       { src = w1; dst = wbf;         off = wblk*1024; }
    else if (wblk < 12) { src = w2; dst = wbf + 8192;  off = (wblk-8)*1024; }
    else if (wblk < 20) { src = w3; dst = wbf + 12288; off = (wblk-12)*1024; }
    else                { src = w4; dst = wbf + 20480; off = (wblk-20)*1024; }
    for (int i = tid; i < 1024; i += 256) dst[off+i] = f2bf(src[off+i]);
  }
}

__global__ void k_fin1(const float* __restrict__ xstat, float* __restrict__ stats1){
  int b = threadIdx.x >> 6, lane = threadIdx.x & 63;
  float s=0.f, s2=0.f;
  #pragma unroll
  for (int j=0;j<4;j++){
    int i = b*256 + j*64 + lane;
    s += xstat[i*2]; s2 += xstat[i*2+1];
  }
  for (int d=1; d<64; d<<=1){ s += __shfl_xor(s,d,64); s2 += __shfl_xor(s2,d,64); }
  if (lane==0){
    float m = s*(1.f/4194304.f);
    float v = s2*(1.f/4194304.f) - m*m;
    stats1[b]=m; stats1[4+b]=rsqrtf(v+EPS_LN);
  }
}

// ---------------- branch1: LN1 + GEMM w1 + dw affine + GLU -> hglu[pos][c] bf16 + p partials ----------------
__global__ __launch_bounds__(256) void k_branch1(
    const float* __restrict__ x, const float* __restrict__ lnw, const float* __restrict__ lnb,
    const short* __restrict__ w1bf, const float* __restrict__ b1,
    const float* __restrict__ dww, const float* __restrict__ dwb,
    const float* __restrict__ stats1, short* __restrict__ hglu, float* __restrict__ ppart)
{
  int b = blockIdx.x >> 10, tile = blockIdx.x & (NPB-1);
  int tid = threadIdx.x, wv = tid>>6, lane = tid&63, l = lane&15, q = lane>>4;
  float mean = stats1[b], rstd = stats1[4+b];
  const float* xb = x + (size_t)b*CH*NP;
  int pos0 = tile*64;

  __shared__ __align__(16) short lin[64*76];   // LN'd bf16, [c][pos] stride 76
  __shared__ float pacc[4][64];

  #pragma unroll
  for (int it=0; it<4; it++){
    int i = it*256 + tid;
    int c = i >> 4, p4 = i & 15;
    size_t idx = (size_t)c*NP + pos0 + p4*4;
    f32x4 xv = *(const f32x4*)(xb + idx);
    f32x4 wv4 = *(const f32x4*)(lnw + idx);
    f32x4 bv4 = *(const f32x4*)(lnb + idx);
    s16x4 pk;
    #pragma unroll
    for (int j=0;j<4;j++) pk[j] = f2bf((xv[j]-mean)*rstd*wv4[j] + bv4[j]);
    *(s16x4*)(&lin[c*76 + p4*4]) = pk;
  }
  __syncthreads();

  bf16x8 bfrag[2];
  #pragma unroll
  for (int ks=0;ks<2;ks++)
    #pragma unroll
    for (int j=0;j<8;j++)
      bfrag[ks][j] = lin[(ks*32+q*8+j)*76 + wv*16 + l];

  f32x4 acc[8];
  #pragma unroll
  for (int mt=0; mt<8; mt++){
    f32x4 a = {0.f,0.f,0.f,0.f};
    #pragma unroll
    for (int ks=0; ks<2; ks++){
      bf16x8 af = *(const bf16x8*)(w1bf + ((mt*16 + l)*CH + ks*32 + q*8));
      a = __builtin_amdgcn_mfma_f32_16x16x32_bf16(af, bfrag[ks], a, 0, 0, 0);
    }
    acc[mt] = a;
  }

  short* hb = hglu + (size_t)b*CH*NP;   // [pos][c] layout
  int pos = pos0 + wv*16 + l;
  float hv[16];
  #pragma unroll
  for (int mt=0; mt<4; mt++){
    s16x4 pk;
    #pragma unroll
    for (int r=0; r<4; r++){
      int oa = mt*16 + q*4 + r, og = oa + 64;
      float av = (acc[mt][r]   + b1[oa]) * dww[oa] + dwb[oa];
      float gv = (acc[mt+4][r] + b1[og]) * dww[og] + dwb[og];
      float h = av * sigmoidf_(gv);
      hv[mt*4+r] = h;
      pk[r] = f2bf(h);
    }
    *(s16x4*)(hb + (size_t)pos*64 + mt*16 + q*4) = pk;
  }
  // channel pooling partials
  #pragma unroll
  for (int i=0;i<16;i++){
    float v = hv[i];
    v += __shfl_xor(v, 1, 64);
    v += __shfl_xor(v, 2, 64);
    v += __shfl_xor(v, 4, 64);
    v += __shfl_xor(v, 8, 64);
    if (l==0){ int mt = i>>2, r = i&3; pacc[wv][mt*16 + q*4 + r] = v; }
  }
  __syncthreads();
  if (tid < 64){
    float s = pacc[0][tid]+pacc[1][tid]+pacc[2][tid]+pacc[3][tid];
    ppart[((size_t)b*NPB + tile)*64 + tid] = s;
  }
}

// ---------------- channel attention MLP + fold s into w2 -> w2s[b] (bf16) ----------------
__global__ __launch_bounds__(256) void k_attn(
    const float* __restrict__ ppart,
    const float* __restrict__ aw1, const float* __restrict__ ab1,
    const float* __restrict__ aw2, const float* __restrict__ ab2,
    const short* __restrict__ w2bf, short* __restrict__ w2s)
{
  int b = blockIdx.x, t = threadIdx.x;
  int c = t & 63, seg = t >> 6;
  const float* pb = ppart + (size_t)b*NPB*64;
  float s = 0.f;
  for (int i = seg; i < NPB; i += 4) s += pb[i*64 + c];
  __shared__ float pl[4][64];
  pl[seg][c] = s;
  __syncthreads();
  __shared__ float parr[64], t1a[64], sarr[64];
  if (t < 64) parr[t] = (pl[0][t]+pl[1][t]+pl[2][t]+pl[3][t]) * (1.f/65536.f);
  __syncthreads();
  if (t < 64){
    float acc = ab1[t];
    for (int k=0;k<64;k++) acc += aw1[t*64+k]*parr[k];
    t1a[t] = fmaxf(acc, 0.f);
  }
  __syncthreads();
  if (t < 64){
    float acc = ab2[t];
    for (int k=0;k<64;k++) acc += aw2[t*64+k]*t1a[k];
    sarr[t] = sigmoidf_(acc);
  }
  __syncthreads();
  for (int i = t; i < 4096; i += 256){
    int cc = i & 63;
    w2s[b*4096 + i] = f2bf(bf2f(w2bf[i]) * sarr[cc]);
  }
}

// ---------------- mid: GEMM w2s + b2 + x -> y (d_out) + y stats partials ----------------
__global__ __launch_bounds__(256) void k_mid(
    const short* __restrict__ hglu, const short* __restrict__ w2s,
    const float* __restrict__ b2, const float* __restrict__ x,
    float* __restrict__ y, float* __restrict__ ystat)
{
  int b = blockIdx.x >> 10, tile = blockIdx.x & (NPB-1);
  int tid = threadIdx.x, wv = tid>>6, lane = tid&63, l = lane&15, q = lane>>4;
  const short* hb = hglu + (size_t)b*CH*NP;
  const short* wa = w2s + b*4096;
  const float* xb = x + (size_t)b*CH*NP;
  float* yb = y + (size_t)b*CH*NP;
  __shared__ __align__(16) float lout[64*65];

  int pos0 = tile*64;
  int posl = wv*16 + l;          // local pos 0..63
  const short* hrow = hb + (size_t)(pos0 + posl)*64;
  bf16x8 bfrag[2];
  bfrag[0] = *(const bf16x8*)(hrow + q*8);
  bfrag[1] = *(const bf16x8*)(hrow + 32 + q*8);

  f32x4 acc[4];
  #pragma unroll
  for (int mt=0; mt<4; mt++){
    f32x4 a = {0.f,0.f,0.f,0.f};
    #pragma unroll
    for (int ks=0; ks<2; ks++){
      bf16x8 af = *(const bf16x8*)(wa + ((mt*16+l)*CH + ks*32 + q*8));
      a = __builtin_amdgcn_mfma_f32_16x16x32_bf16(af, bfrag[ks], a, 0, 0, 0);
    }
    acc[mt] = a;
  }
  #pragma unroll
  for (int mt=0; mt<4; mt++)
    #pragma unroll
    for (int r=0;r<4;r++){
      int o = mt*16 + q*4 + r;
      lout[posl*65 + o] = acc[mt][r] + b2[o];
    }
  __syncthreads();

  float s1 = 0.f, s2 = 0.f;
  #pragma unroll
  for (int it=0; it<4; it++){
    int i = it*256 + tid;
    int c = i >> 4, p4 = i & 15;
    size_t idx = (size_t)c*NP + pos0 + p4*4;
    f32x4 xv = *(const f32x4*)(xb + idx);
    f32x4 yv;
    #pragma unroll
    for (int j=0;j<4;j++){
      float v = lout[(p4*4+j)*65 + c] + xv[j];
      yv[j] = v; s1 += v; s2 += v*v;
    }
    *(f32x4*)(yb + idx) = yv;
  }
  for (int d=1; d<64; d<<=1){ s1 += __shfl_xor(s1,d,64); s2 += __shfl_xor(s2,d,64); }
  __shared__ float red[8];
  if (lane==0){ red[wv]=s1; red[4+wv]=s2; }
  __syncthreads();
  if (tid==0){
    ystat[(size_t)blockIdx.x*2]   = red[0]+red[1]+red[2]+red[3];
    ystat[(size_t)blockIdx.x*2+1] = red[4]+red[5]+red[6]+red[7];
  }
}

__global__ void k_fin2(const float* __restrict__ ystat, float* __restrict__ stats2){
  int t = threadIdx.x;           // 256
  int b = t >> 6, i0 = t & 63;
  float s=0.f, s2=0.f;
  for (int i=i0; i<NPB; i+=64){
    s  += ystat[((size_t)b*NPB+i)*2];
    s2 += ystat[((size_t)b*NPB+i)*2+1];
  }
  __shared__ float ls[4][64], l2[4][64];
  ls[b][i0]=s; l2[b][i0]=s2;
  __syncthreads();
  if (t < 4){
    float ts=0.f, t2=0.f;
    for (int i=0;i<64;i++){ ts+=ls[t][i]; t2+=l2[t][i]; }
    float m = ts*(1.f/4194304.f);
    float v = t2*(1.f/4194304.f) - m*m;
    stats2[t]=m; stats2[4+t]=rsqrtf(v+EPS_LN);
  }
}

// ---------------- branch2: LN2 + GEMM w3 + GLU + GEMM w4 + residual (in-place over y) ----------------
__global__ __launch_bounds__(256) void k_branch2(
    float* yio, const float* __restrict__ lnw, const float* __restrict__ lnb,
    const short* __restrict__ w3bf, const float* __restrict__ b3,
    const short* __restrict__ w4bf, const float* __restrict__ b4,
    const float* __restrict__ stats2)
{
  int b = blockIdx.x >> 10, tile = blockIdx.x & (NPB-1);
  int tid = threadIdx.x, wv = tid>>6, lane = tid&63, l = lane&15, q = lane>>4;
  float mean = stats2[b], rstd = stats2[4+b];
  float* yb = yio + (size_t)b*CH*NP;
  int pos0 = tile*64;

  __shared__ __align__(16) char smem[64*65*4];   // union: lin(9728) / lglu(9216) / lout(16640)
  short* lin  = (short*)smem;    // [c][pos] stride 76, LN'd bf16
  short* lglu = (short*)smem;    // [pos][c] stride 72, GLU bf16
  float* lout = (float*)smem;    // [pos][c] stride 65, fp32 out

  float yr[16];
  #pragma unroll
  for (int it=0; it<4; it++){
    int i = it*256 + tid;
    int c = i >> 4, p4 = i & 15;
    size_t idx = (size_t)c*NP + pos0 + p4*4;
    f32x4 yv = *(const f32x4*)(yb + idx);
    f32x4 wv4 = *(const f32x4*)(lnw + idx);
    f32x4 bv4 = *(const f32x4*)(lnb + idx);
    s16x4 pk;
    #pragma unroll
    for (int j=0;j<4;j++){
      yr[it*4+j] = yv[j];
      pk[j] = f2bf((yv[j]-mean)*rstd*wv4[j] + bv4[j]);
    }
    *(s16x4*)(&lin[c*76 + p4*4]) = pk;
  }
  __syncthreads();

  bf16x8 bfrag[2];
  #pragma unroll
  for (int ks=0;ks<2;ks++)
    #pragma unroll
    for (int j=0;j<8;j++)
      bfrag[ks][j] = lin[(ks*32+q*8+j)*76 + wv*16 + l];
  __syncthreads();   // lin dead after this point

  f32x4 acc[8];
  #pragma unroll
  for (int mt=0; mt<8; mt++){
    f32x4 a = {0.f,0.f,0.f,0.f};
    #pragma unroll
    for (int ks=0; ks<2; ks++){
      bf16x8 af = *(const bf16x8*)(w3bf + ((mt*16 + l)*CH + ks*32 + q*8));
      a = __builtin_amdgcn_mfma_f32_16x16x32_bf16(af, bfrag[ks], a, 0, 0, 0);
    }
    acc[mt] = a;
  }

  int posl = wv*16 + l;
  #pragma unroll
  for (int mt=0; mt<4; mt++){
    s16x4 pk;
    #pragma unroll
    for (int r=0; r<4; r++){
      int c = mt*16 + q*4 + r;
      float av = acc[mt][r]   + b3[c];
      float gv = acc[mt+4][r] + b3[c+64];
      pk[r] = f2bf(av * sigmoidf_(gv));
    }
    *(s16x4*)(&lglu[posl*72 + mt*16 + q*4]) = pk;
  }
  __syncthreads();

  bf16x8 pfrag[2];
  pfrag[0] = *(const bf16x8*)(&lglu[posl*72 + q*8]);
  pfrag[1] = *(const bf16x8*)(&lglu[posl*72 + 32 + q*8]);
  __syncthreads();   // lglu dead

  f32x4 acc2[4];
  #pragma unroll
  for (int mt=0; mt<4; mt++){
    f32x4 a = {0.f,0.f,0.f,0.f};
    #pragma unroll
    for (int ks=0; ks<2; ks++){
      bf16x8 af = *(const bf16x8*)(w4bf + ((mt*16+l)*CH + ks*32 + q*8));
      a = __builtin_amdgcn_mfma_f32_16x16x32_bf16(af, pfrag[ks], a, 0, 0, 0);
    }
    acc2[mt] = a;
  }
  #pragma unroll
  for (int mt=0; mt<4; mt++)
    #pragma unroll
    for (int r=0;r<4;r++){
      int o = mt*16 + q*4 + r;
      lout[posl*65 + o] = acc2[mt][r] + b4[o];
    }
  __syncthreads();

  #pragma unroll
  for (int it=0; it<4; it++){
    int i = it*256 + tid;
    int c = i >> 4, p4 = i & 15;
    size_t idx = (size_t)c*NP + pos0 + p4*4;
    f32x4 yv;
    #pragma unroll
    for (int j=0;j<4;j++) yv[j] = lout[(p4*4+j)*65 + c] + yr[it*4+j];
    *(f32x4*)(yb + idx) = yv;
  }
}

extern "C" void kernel_launch(void* const* d_in, const int* in_sizes, int n_in,
                              void* d_out, int out_size, void* d_ws, size_t ws_size,
                              hipStream_t stream){
  const float* x    = (const float*)d_in[0];
  const float* ln1w = (const float*)d_in[1];
  const float* ln1b = (const float*)d_in[2];
  const float* ln2w = (const float*)d_in[3];
  const float* ln2b = (const float*)d_in[4];
  const float* w1   = (const float*)d_in[5];
  const float* b1   = (const float*)d_in[6];
  const float* dww  = (const float*)d_in[7];
  const float* dwb  = (const float*)d_in[8];
  const float* aw1  = (const float*)d_in[9];
  const float* ab1  = (const float*)d_in[10];
  const float* aw2  = (const float*)d_in[11];
  const float* ab2  = (const float*)d_in[12];
  const float* w2   = (const float*)d_in[13];
  const float* b2   = (const float*)d_in[14];
  const float* w3   = (const float*)d_in[15];
  const float* b3   = (const float*)d_in[16];
  const float* w4   = (const float*)d_in[17];
  const float* b4   = (const float*)d_in[18];
  float* out = (float*)d_out;
  float* ws  = (float*)d_ws;

  // ws layout (float offsets)
  float* xstat  = ws;                     // 2048
  float* stats1 = ws + 2048;              // 8
  float* ystat  = ws + 2112;              // 8192
  float* stats2 = ws + 10304;             // 8
  short* wbf    = (short*)(ws + 10368);   // 24576 bf16: w1|w2|w3|w4
  short* w2s    = (short*)(ws + 22656);   // 16384 bf16: per-batch scaled w2
  float* ppart  = ws + 30848;             // 262144
  short* hglu   = (short*)(ws + 292992);  // 16777216 bf16 [b][pos][c]; total ~34.7 MB

  hipLaunchKernelGGL(k_prep,    dim3(1048), dim3(256), 0, stream, x, w1, w2, w3, w4, xstat, wbf);
  hipLaunchKernelGGL(k_fin1,    dim3(1),    dim3(256), 0, stream, xstat, stats1);
  hipLaunchKernelGGL(k_branch1, dim3(4096), dim3(256), 0, stream, x, ln1w, ln1b, wbf, b1, dww, dwb, stats1, hglu, ppart);
  hipLaunchKernelGGL(k_attn,    dim3(4),    dim3(256), 0, stream, ppart, aw1, ab1, aw2, ab2, wbf + 8192, w2s);
  hipLaunchKernelGGL(k_mid,     dim3(4096), dim3(256), 0, stream, hglu, w2s, b2, x, out, ystat);
  hipLaunchKernelGGL(k_fin2,    dim3(1),    dim3(256), 0, stream, ystat, stats2);
  hipLaunchKernelGGL(k_branch2, dim3(4096), dim3(256), 0, stream, out, ln2w, ln2b, wbf + 12288, b3, wbf + 20480, b4, stats2);
}

// Round 4
// 347.902 us; speedup vs baseline: 1.2364x; 1.1866x over previous
//
#include <hip/hip_runtime.h>
#include <cstdint>
#include <cstddef>

#define CH 64
#define NP 65536          // F*S
#define NPB 1024          // 64-pos tiles per batch
constexpr float EPS_LN = 1e-5f;

using f32x4  = __attribute__((ext_vector_type(4))) float;
using bf16x8 = __attribute__((ext_vector_type(8))) short;
using s16x4  = __attribute__((ext_vector_type(4))) short;
using s16x2  = __attribute__((ext_vector_type(2))) short;

__device__ __forceinline__ short f2bf(float f){
  union { float f; uint32_t u; } v; v.f = f;
  uint32_t r = v.u + 0x7FFFu + ((v.u >> 16) & 1u);
  return (short)(r >> 16);
}
__device__ __forceinline__ float bf2f(short s){
  union { uint32_t u; float f; } v; v.u = ((uint32_t)(uint16_t)s) << 16;
  return v.f;
}
__device__ __forceinline__ float sigmoidf_(float x){ return 1.f/(1.f+__expf(-x)); }

// LDS-only barrier: waits lgkmcnt(0) but leaves vmcnt (global prefetch) in flight.
// All cross-wave traffic in these kernels goes through LDS, so this is sufficient.
__device__ __forceinline__ void lds_barrier(){
  asm volatile("s_waitcnt lgkmcnt(0)\n\ts_barrier" ::: "memory");
}

// ---------------- prep: x stats partials (1024 blks) + bf16 weight conversion ----------------
__global__ __launch_bounds__(256) void k_prep(
    const float* __restrict__ x,
    const float* __restrict__ w1, const float* __restrict__ w2,
    const float* __restrict__ w3, const float* __restrict__ w4,
    float* __restrict__ xstat, short* __restrict__ wbf)
{
  int blk = blockIdx.x, tid = threadIdx.x;
  if (blk < 1024) {
    int b = blk >> 8, chunk = blk & 255;
    const float* base = x + (size_t)b*CH*NP + (size_t)chunk*16384;
    float s = 0.f, s2 = 0.f;
    for (int i = tid*4; i < 16384; i += 1024) {
      f32x4 v = *(const f32x4*)(base + i);
      s  += v.x + v.y + v.z + v.w;
      s2 += v.x*v.x + v.y*v.y + v.z*v.z + v.w*v.w;
    }
    for (int d=1; d<64; d<<=1){ s += __shfl_xor(s,d,64); s2 += __shfl_xor(s2,d,64); }
    __shared__ float ls[8];
    int wv = tid>>6;
    if ((tid&63)==0){ ls[wv]=s; ls[4+wv]=s2; }
    __syncthreads();
    if (tid==0){
      xstat[blk*2]   = ls[0]+ls[1]+ls[2]+ls[3];
      xstat[blk*2+1] = ls[4]+ls[5]+ls[6]+ls[7];
    }
  } else {
    int wblk = blk - 1024;  // 24 blocks x 1024 elems
    const float* src; short* dst; int off;
    if (wblk < 8)       { src = w1; dst = wbf;         off = wblk*1024; }
    else if (wblk < 12) { src = w2; dst = wbf + 8192;  off = (wblk-8)*1024; }
    else if (wblk < 20) { src = w3; dst = wbf + 12288; off = (wblk-12)*1024; }
    else                { src = w4; dst = wbf + 20480; off = (wblk-20)*1024; }
    for (int i = tid; i < 1024; i += 256) dst[off+i] = f2bf(src[off+i]);
  }
}

__global__ void k_fin1(const float* __restrict__ xstat, float* __restrict__ stats1){
  int b = threadIdx.x >> 6, lane = threadIdx.x & 63;
  float s=0.f, s2=0.f;
  #pragma unroll
  for (int j=0;j<4;j++){
    int i = b*256 + j*64 + lane;
    s += xstat[i*2]; s2 += xstat[i*2+1];
  }
  for (int d=1; d<64; d<<=1){ s += __shfl_xor(s,d,64); s2 += __shfl_xor(s2,d,64); }
  if (lane==0){
    float m = s*(1.f/4194304.f);
    float v = s2*(1.f/4194304.f) - m*m;
    stats1[b]=m; stats1[4+b]=rsqrtf(v+EPS_LN);
  }
}

// ---------------- branch1: LN1 + GEMM w1(*dww folded) + GLU -> hglu[pos][c] + p partials ----------------
__global__ __launch_bounds__(256,4) void k_branch1(
    const float* __restrict__ x, const float* __restrict__ lnw, const float* __restrict__ lnb,
    const short* __restrict__ w1bf, const float* __restrict__ b1,
    const float* __restrict__ dww, const float* __restrict__ dwb,
    const float* __restrict__ stats1, short* __restrict__ hglu, float* __restrict__ ppart)
{
  int blk = blockIdx.x;                 // 1024
  int b = blk >> 8;
  int tile0 = (blk & 255) * 4;
  int tid = threadIdx.x, wv = tid>>6, lane = tid&63, l = lane&15, q = lane>>4;
  int c_ = tid>>4, p4 = tid&15;
  float mean = stats1[b], rstd = stats1[4+b];
  const float* xb = x + (size_t)b*CH*NP;
  short* hb = hglu + (size_t)b*CH*NP;   // [pos][c]

  __shared__ __align__(16) short wlds[8192];   // w1*dww, fragment-linear
  __shared__ __align__(16) short lin[64*78];   // LN'd bf16, [c][pos] stride 78
  __shared__ float pacc[4][64];
  __shared__ __align__(16) float cc[128];      // b1*dww + dwb

  // stage weights (fragment order: g = mt*128 + ks*64 + q*16 + l, 8 elems each)
  #pragma unroll
  for (int g0=0; g0<4; g0++){
    int g = g0*256 + tid;
    int mt = g>>7, ks = (g>>6)&1, qq = (g>>4)&3, ll = g&15;
    int m = mt*16 + ll;
    float sc = dww[m];
    bf16x8 w8 = *(const bf16x8*)(w1bf + (m*CH + ks*32 + qq*8));
    #pragma unroll
    for (int j=0;j<8;j++) w8[j] = f2bf(bf2f(w8[j]) * sc);
    *(bf16x8*)(&wlds[g*8]) = w8;
  }
  if (tid < 128) cc[tid] = b1[tid]*dww[tid] + dwb[tid];
  // first use of wlds/cc is after barrier A of tile 0 — no extra barrier needed here

  // initial prefetch (tile 0)
  f32x4 pX[4], pW[4], pB[4];
  #pragma unroll
  for (int it=0; it<4; it++){
    int c = it*16 + c_;
    size_t o = (size_t)c*NP + tile0*64 + p4*4;
    pX[it] = *(const f32x4*)(xb + o);
    pW[it] = *(const f32x4*)(lnw + o);
    pB[it] = *(const f32x4*)(lnb + o);
  }

  for (int t=0; t<4; t++){
    int pos0 = (tile0 + t)*64;
    // stage-in: LN -> lin
    #pragma unroll
    for (int it=0; it<4; it++){
      int c = it*16 + c_;
      s16x2 lo, hi;
      lo[0] = f2bf((pX[it][0]-mean)*rstd*pW[it][0] + pB[it][0]);
      lo[1] = f2bf((pX[it][1]-mean)*rstd*pW[it][1] + pB[it][1]);
      hi[0] = f2bf((pX[it][2]-mean)*rstd*pW[it][2] + pB[it][2]);
      hi[1] = f2bf((pX[it][3]-mean)*rstd*pW[it][3] + pB[it][3]);
      *(s16x2*)(&lin[c*78 + p4*4])     = lo;
      *(s16x2*)(&lin[c*78 + p4*4 + 2]) = hi;
    }
    // prefetch next tile (in flight across the barriers below)
    if (t < 3){
      #pragma unroll
      for (int it=0; it<4; it++){
        int c = it*16 + c_;
        size_t o = (size_t)c*NP + pos0 + 64 + p4*4;
        pX[it] = *(const f32x4*)(xb + o);
        pW[it] = *(const f32x4*)(lnw + o);
        pB[it] = *(const f32x4*)(lnb + o);
      }
    }
    lds_barrier();   // A: lin (and, at t=0, wlds/cc) visible

    bf16x8 bfrag[2];
    #pragma unroll
    for (int ks=0; ks<2; ks++)
      #pragma unroll
      for (int j=0; j<8; j++)
        bfrag[ks][j] = lin[(ks*32+q*8+j)*78 + wv*16 + l];

    f32x4 acc[8];
    #pragma unroll
    for (int mt=0; mt<8; mt++){
      f32x4 a = {0.f,0.f,0.f,0.f};
      #pragma unroll
      for (int ks=0; ks<2; ks++){
        bf16x8 af = *(const bf16x8*)(&wlds[(mt*128 + ks*64 + q*16 + l)*8]);
        a = __builtin_amdgcn_mfma_f32_16x16x32_bf16(af, bfrag[ks], a, 0, 0, 0);
      }
      acc[mt] = a;
    }

    int pos = pos0 + wv*16 + l;
    #pragma unroll
    for (int mt=0; mt<4; mt++){
      f32x4 ccA = *(const f32x4*)(&cc[mt*16 + q*4]);
      f32x4 ccG = *(const f32x4*)(&cc[64 + mt*16 + q*4]);
      s16x4 pk; float hv[4];
      #pragma unroll
      for (int r=0; r<4; r++){
        float av = acc[mt][r]   + ccA[r];
        float gv = acc[mt+4][r] + ccG[r];
        float h = av * sigmoidf_(gv);
        hv[r] = h; pk[r] = f2bf(h);
      }
      *(s16x4*)(hb + (size_t)pos*CH + mt*16 + q*4) = pk;
      #pragma unroll
      for (int r=0; r<4; r++){
        float v = hv[r];
        v += __shfl_xor(v,1,64); v += __shfl_xor(v,2,64);
        v += __shfl_xor(v,4,64); v += __shfl_xor(v,8,64);
        if (l==0) pacc[wv][mt*16 + q*4 + r] = v;
      }
    }
    lds_barrier();   // B: bfrag reads done (lin reusable) + pacc visible
    if (tid < 64){
      float s = pacc[0][tid]+pacc[1][tid]+pacc[2][tid]+pacc[3][tid];
      ppart[((size_t)b*NPB + tile0 + t)*64 + tid] = s;
    }
  }
}

// ---------------- channel attention MLP + fold s into w2 -> w2s[b] (bf16) ----------------
__global__ __launch_bounds__(256) void k_attn(
    const float* __restrict__ ppart,
    const float* __restrict__ aw1, const float* __restrict__ ab1,
    const float* __restrict__ aw2, const float* __restrict__ ab2,
    const short* __restrict__ w2bf, short* __restrict__ w2s)
{
  int b = blockIdx.x, t = threadIdx.x;
  int c = t & 63, seg = t >> 6;
  const float* pb = ppart + (size_t)b*NPB*64;
  float s = 0.f;
  for (int i = seg; i < NPB; i += 4) s += pb[i*64 + c];
  __shared__ float pl[4][64];
  pl[seg][c] = s;
  __syncthreads();
  __shared__ float parr[64], t1a[64], sarr[64];
  if (t < 64) parr[t] = (pl[0][t]+pl[1][t]+pl[2][t]+pl[3][t]) * (1.f/65536.f);
  __syncthreads();
  if (t < 64){
    float acc = ab1[t];
    for (int k=0;k<64;k++) acc += aw1[t*64+k]*parr[k];
    t1a[t] = fmaxf(acc, 0.f);
  }
  __syncthreads();
  if (t < 64){
    float acc = ab2[t];
    for (int k=0;k<64;k++) acc += aw2[t*64+k]*t1a[k];
    sarr[t] = sigmoidf_(acc);
  }
  __syncthreads();
  for (int i = t; i < 4096; i += 256){
    int cc = i & 63;
    w2s[b*4096 + i] = f2bf(bf2f(w2bf[i]) * sarr[cc]);
  }
}

// ---------------- mid: GEMM w2s + b2 + x -> y (d_out) + y stats partials ----------------
__global__ __launch_bounds__(256,4) void k_mid(
    const short* __restrict__ hglu, const short* __restrict__ w2s,
    const float* __restrict__ b2, const float* __restrict__ x,
    float* __restrict__ y, float* __restrict__ ystat)
{
  int blk = blockIdx.x;                 // 1024
  int b = blk >> 8;
  int tile0 = (blk & 255) * 4;
  int tid = threadIdx.x, wv = tid>>6, lane = tid&63, l = lane&15, q = lane>>4;
  int c_ = tid>>4, p4 = tid&15;
  const short* hb = hglu + (size_t)b*CH*NP;
  const float* xb = x + (size_t)b*CH*NP;
  float* yb = y + (size_t)b*CH*NP;
  int posl = wv*16 + l;

  __shared__ __align__(16) short w2l[4096];
  __shared__ __align__(16) float lout[64*65];

  #pragma unroll
  for (int g0=0; g0<2; g0++){
    int g = g0*256 + tid;
    int mt = g>>7, ks = (g>>6)&1, qq = (g>>4)&3, ll = g&15;
    *(bf16x8*)(&w2l[g*8]) = *(const bf16x8*)(w2s + b*4096 + (mt*16+ll)*CH + ks*32 + qq*8);
  }
  float b2v[4];
  #pragma unroll
  for (int it=0; it<4; it++) b2v[it] = b2[it*16 + c_];

  // initial prefetch (issued before the staging barrier so loads are in flight)
  bf16x8 pH0, pH1; f32x4 pXr[4];
  {
    const short* hr = hb + (size_t)(tile0*64 + posl)*CH;
    pH0 = *(const bf16x8*)(hr + q*8);
    pH1 = *(const bf16x8*)(hr + 32 + q*8);
    #pragma unroll
    for (int it=0; it<4; it++)
      pXr[it] = *(const f32x4*)(xb + (size_t)(it*16+c_)*NP + tile0*64 + p4*4);
  }
  lds_barrier();   // S: w2l staged by ALL threads visible before first MFMA (round-3 bug fix)

  float s1 = 0.f, s2 = 0.f;

  for (int t=0; t<4; t++){
    int pos0 = (tile0 + t)*64;
    bf16x8 h0 = pH0, h1 = pH1;
    if (t < 3){
      const short* hr = hb + (size_t)(pos0 + 64 + posl)*CH;
      pH0 = *(const bf16x8*)(hr + q*8);
      pH1 = *(const bf16x8*)(hr + 32 + q*8);
    }
    f32x4 acc[4];
    #pragma unroll
    for (int mt=0; mt<4; mt++){
      f32x4 a = {0.f,0.f,0.f,0.f};
      a = __builtin_amdgcn_mfma_f32_16x16x32_bf16(
            *(const bf16x8*)(&w2l[(mt*128 + 0*64 + q*16 + l)*8]), h0, a, 0,0,0);
      a = __builtin_amdgcn_mfma_f32_16x16x32_bf16(
            *(const bf16x8*)(&w2l[(mt*128 + 1*64 + q*16 + l)*8]), h1, a, 0,0,0);
      acc[mt] = a;
    }
    #pragma unroll
    for (int mt=0; mt<4; mt++)
      #pragma unroll
      for (int r=0; r<4; r++)
        lout[posl*65 + mt*16 + q*4 + r] = acc[mt][r];
    lds_barrier();   // B1: lout visible

    f32x4 yv[4];
    #pragma unroll
    for (int it=0; it<4; it++){
      int c = it*16 + c_;
      #pragma unroll
      for (int j=0; j<4; j++){
        float v = lout[(p4*4+j)*65 + c] + b2v[it] + pXr[it][j];
        yv[it][j] = v; s1 += v; s2 += v*v;
      }
    }
    if (t < 3){
      #pragma unroll
      for (int it=0; it<4; it++)
        pXr[it] = *(const f32x4*)(xb + (size_t)(it*16+c_)*NP + pos0 + 64 + p4*4);
    }
    #pragma unroll
    for (int it=0; it<4; it++)
      *(f32x4*)(yb + (size_t)(it*16+c_)*NP + pos0 + p4*4) = yv[it];
    lds_barrier();   // B2: lout reads done before next tile's writes
  }

  for (int d=1; d<64; d<<=1){ s1 += __shfl_xor(s1,d,64); s2 += __shfl_xor(s2,d,64); }
  __shared__ float red[8];
  if (lane==0){ red[wv]=s1; red[4+wv]=s2; }
  __syncthreads();
  if (tid==0){
    ystat[(size_t)blk*2]   = red[0]+red[1]+red[2]+red[3];
    ystat[(size_t)blk*2+1] = red[4]+red[5]+red[6]+red[7];
  }
}

__global__ void k_fin2(const float* __restrict__ ystat, float* __restrict__ stats2){
  int t = threadIdx.x;           // 256
  int b = t >> 6, lane = t & 63;
  float s=0.f, s2=0.f;
  #pragma unroll
  for (int j=0;j<4;j++){
    int e = b*256 + j*64 + lane;
    s  += ystat[e*2];
    s2 += ystat[e*2+1];
  }
  for (int d=1; d<64; d<<=1){ s += __shfl_xor(s,d,64); s2 += __shfl_xor(s2,d,64); }
  if (lane==0){
    float m = s*(1.f/4194304.f);
    float v = s2*(1.f/4194304.f) - m*m;
    stats2[b]=m; stats2[4+b]=rsqrtf(v+EPS_LN);
  }
}

// ---------------- branch2: LN2 + GEMM w3 + GLU + GEMM w4 + residual (in-place over y) ----------------
__global__ __launch_bounds__(256,3) void k_branch2(
    float* __restrict__ yio, const float* __restrict__ lnw, const float* __restrict__ lnb,
    const short* __restrict__ w3bf, const float* __restrict__ b3,
    const short* __restrict__ w4bf, const float* __restrict__ b4,
    const float* __restrict__ stats2)
{
  int blk = blockIdx.x;                 // 1024
  int b = blk >> 8;
  int tile0 = (blk & 255) * 4;
  int tid = threadIdx.x, wv = tid>>6, lane = tid&63, l = lane&15, q = lane>>4;
  int c_ = tid>>4, p4 = tid&15;
  float mean = stats2[b], rstd = stats2[4+b];
  float* yb = yio + (size_t)b*CH*NP;
  int posl = wv*16 + l;

  __shared__ __align__(16) short w3l[8192];
  __shared__ __align__(16) short w4l[4096];
  __shared__ __align__(16) short lin[64*78];
  __shared__ __align__(16) char lun[64*65*4];   // lglu (short, stride 72) ∪ lout (float, stride 65)
  short* lglu = (short*)lun;
  float* lout = (float*)lun;
  __shared__ __align__(16) float b3l[128];

  #pragma unroll
  for (int g0=0; g0<4; g0++){
    int g = g0*256 + tid;
    int mt = g>>7, ks = (g>>6)&1, qq = (g>>4)&3, ll = g&15;
    *(bf16x8*)(&w3l[g*8]) = *(const bf16x8*)(w3bf + ((mt*16+ll)*CH + ks*32 + qq*8));
  }
  #pragma unroll
  for (int g0=0; g0<2; g0++){
    int g = g0*256 + tid;
    int mt = g>>7, ks = (g>>6)&1, qq = (g>>4)&3, ll = g&15;
    *(bf16x8*)(&w4l[g*8]) = *(const bf16x8*)(w4bf + ((mt*16+ll)*CH + ks*32 + qq*8));
  }
  if (tid < 128) b3l[tid] = b3[tid];
  float b4v[4];
  #pragma unroll
  for (int it=0; it<4; it++) b4v[it] = b4[it*16 + c_];
  // first use of w3l/b3l is after barrier A; w4l after barrier C — covered

  // initial prefetch
  f32x4 pY[4], pW[4], pB[4];
  #pragma unroll
  for (int it=0; it<4; it++){
    int c = it*16 + c_;
    size_t o = (size_t)c*NP + tile0*64 + p4*4;
    pY[it] = *(const f32x4*)(yb + o);
    pW[it] = *(const f32x4*)(lnw + o);
    pB[it] = *(const f32x4*)(lnb + o);
  }

  for (int t=0; t<4; t++){
    int pos0 = (tile0 + t)*64;
    // stage-in: LN -> lin   (pY kept for residual)
    #pragma unroll
    for (int it=0; it<4; it++){
      int c = it*16 + c_;
      s16x2 lo, hi;
      lo[0] = f2bf((pY[it][0]-mean)*rstd*pW[it][0] + pB[it][0]);
      lo[1] = f2bf((pY[it][1]-mean)*rstd*pW[it][1] + pB[it][1]);
      hi[0] = f2bf((pY[it][2]-mean)*rstd*pW[it][2] + pB[it][2]);
      hi[1] = f2bf((pY[it][3]-mean)*rstd*pW[it][3] + pB[it][3]);
      *(s16x2*)(&lin[c*78 + p4*4])     = lo;
      *(s16x2*)(&lin[c*78 + p4*4 + 2]) = hi;
    }
    if (t < 3){
      #pragma unroll
      for (int it=0; it<4; it++){
        int c = it*16 + c_;
        size_t o = (size_t)c*NP + pos0 + 64 + p4*4;
        pW[it] = *(const f32x4*)(lnw + o);
        pB[it] = *(const f32x4*)(lnb + o);
      }
    }
    lds_barrier();   // A: lin visible (also covers w3l/b3l at t=0; prior-tile lout reads done)

    bf16x8 bfrag[2];
    #pragma unroll
    for (int ks=0; ks<2; ks++)
      #pragma unroll
      for (int j=0; j<8; j++)
        bfrag[ks][j] = lin[(ks*32+q*8+j)*78 + wv*16 + l];

    f32x4 acc[8];
    #pragma unroll
    for (int mt=0; mt<8; mt++){
      f32x4 a = {0.f,0.f,0.f,0.f};
      #pragma unroll
      for (int ks=0; ks<2; ks++){
        bf16x8 af = *(const bf16x8*)(&w3l[(mt*128 + ks*64 + q*16 + l)*8]);
        a = __builtin_amdgcn_mfma_f32_16x16x32_bf16(af, bfrag[ks], a, 0, 0, 0);
      }
      acc[mt] = a;
    }

    // GLU -> lglu
    #pragma unroll
    for (int mt=0; mt<4; mt++){
      f32x4 bA = *(const f32x4*)(&b3l[mt*16 + q*4]);
      f32x4 bG = *(const f32x4*)(&b3l[64 + mt*16 + q*4]);
      s16x4 pk;
      #pragma unroll
      for (int r=0; r<4; r++){
        float av = acc[mt][r]   + bA[r];
        float gv = acc[mt+4][r] + bG[r];
        pk[r] = f2bf(av * sigmoidf_(gv));
      }
      *(s16x4*)(&lglu[posl*72 + mt*16 + q*4]) = pk;
    }
    lds_barrier();   // C: lglu visible (also covers w4l at t=0)

    bf16x8 pfrag[2];
    pfrag[0] = *(const bf16x8*)(&lglu[posl*72 + q*8]);
    pfrag[1] = *(const bf16x8*)(&lglu[posl*72 + 32 + q*8]);
    lds_barrier();   // C2: pfrag reads done before lout overwrites the union

    f32x4 acc2[4];
    #pragma unroll
    for (int mt=0; mt<4; mt++){
      f32x4 a = {0.f,0.f,0.f,0.f};
      #pragma unroll
      for (int ks=0; ks<2; ks++){
        bf16x8 af = *(const bf16x8*)(&w4l[(mt*128 + ks*64 + q*16 + l)*8]);
        a = __builtin_amdgcn_mfma_f32_16x16x32_bf16(af, ks ? pfrag[1] : pfrag[0], a, 0, 0, 0);
      }
      acc2[mt] = a;
    }
    #pragma unroll
    for (int mt=0; mt<4; mt++)
      #pragma unroll
      for (int r=0; r<4; r++)
        lout[posl*65 + mt*16 + q*4 + r] = acc2[mt][r];
    lds_barrier();   // D: lout visible

    f32x4 yv[4];
    #pragma unroll
    for (int it=0; it<4; it++){
      int c = it*16 + c_;
      #pragma unroll
      for (int j=0; j<4; j++)
        yv[it][j] = lout[(p4*4+j)*65 + c] + b4v[it] + pY[it][j];
    }
    if (t < 3){
      #pragma unroll
      for (int it=0; it<4; it++){
        int c = it*16 + c_;
        pY[it] = *(const f32x4*)(yb + (size_t)c*NP + pos0 + 64 + p4*4);
      }
    }
    #pragma unroll
    for (int it=0; it<4; it++)
      *(f32x4*)(yb + (size_t)(it*16+c_)*NP + pos0 + p4*4) = yv[it];
  }
}

extern "C" void kernel_launch(void* const* d_in, const int* in_sizes, int n_in,
                              void* d_out, int out_size, void* d_ws, size_t ws_size,
                              hipStream_t stream){
  const float* x    = (const float*)d_in[0];
  const float* ln1w = (const float*)d_in[1];
  const float* ln1b = (const float*)d_in[2];
  const float* ln2w = (const float*)d_in[3];
  const float* ln2b = (const float*)d_in[4];
  const float* w1   = (const float*)d_in[5];
  const float* b1   = (const float*)d_in[6];
  const float* dww  = (const float*)d_in[7];
  const float* dwb  = (const float*)d_in[8];
  const float* aw1  = (const float*)d_in[9];
  const float* ab1  = (const float*)d_in[10];
  const float* aw2  = (const float*)d_in[11];
  const float* ab2  = (const float*)d_in[12];
  const float* w2   = (const float*)d_in[13];
  const float* b2   = (const float*)d_in[14];
  const float* w3   = (const float*)d_in[15];
  const float* b3   = (const float*)d_in[16];
  const float* w4   = (const float*)d_in[17];
  const float* b4   = (const float*)d_in[18];
  float* out = (float*)d_out;
  float* ws  = (float*)d_ws;

  // ws layout (float offsets)
  float* xstat  = ws;                     // 2048
  float* stats1 = ws + 2048;              // 8
  float* ystat  = ws + 2112;              // 2048
  float* stats2 = ws + 10304;             // 8
  short* wbf    = (short*)(ws + 10368);   // 24576 bf16: w1|w2|w3|w4
  short* w2s    = (short*)(ws + 22656);   // 16384 bf16: per-batch scaled w2
  float* ppart  = ws + 30848;             // 262144
  short* hglu   = (short*)(ws + 292992);  // 16777216 bf16 [b][pos][c]; total ~34.7 MB

  hipLaunchKernelGGL(k_prep,    dim3(1048), dim3(256), 0, stream, x, w1, w2, w3, w4, xstat, wbf);
  hipLaunchKernelGGL(k_fin1,    dim3(1),    dim3(256), 0, stream, xstat, stats1);
  hipLaunchKernelGGL(k_branch1, dim3(1024), dim3(256), 0, stream, x, ln1w, ln1b, wbf, b1, dww, dwb, stats1, hglu, ppart);
  hipLaunchKernelGGL(k_attn,    dim3(4),    dim3(256), 0, stream, ppart, aw1, ab1, aw2, ab2, wbf + 8192, w2s);
  hipLaunchKernelGGL(k_mid,     dim3(1024), dim3(256), 0, stream, hglu, w2s, b2, x, out, ystat);
  hipLaunchKernelGGL(k_fin2,    dim3(1),    dim3(256), 0, stream, ystat, stats2);
  hipLaunchKernelGGL(k_branch2, dim3(1024), dim3(256), 0, stream, out, ln2w, ln2b, wbf + 12288, b3, wbf + 20480, b4, stats2);
}

// Round 5
// 281.510 us; speedup vs baseline: 1.5281x; 1.2358x over previous
//
#include <hip/hip_runtime.h>
#include <cstdint>
#include <cstddef>

#define CH 64
#define NP 65536          // F*S
#define NPB 1024          // 64-pos tiles per batch
constexpr float EPS_LN = 1e-5f;

using f32x4  = __attribute__((ext_vector_type(4))) float;
using bf16x8 = __attribute__((ext_vector_type(8))) short;
using s16x4  = __attribute__((ext_vector_type(4))) short;
using s16x2  = __attribute__((ext_vector_type(2))) short;

__device__ __forceinline__ short f2bf(float f){
  union { float f; uint32_t u; } v; v.f = f;
  uint32_t r = v.u + 0x7FFFu + ((v.u >> 16) & 1u);
  return (short)(r >> 16);
}
__device__ __forceinline__ float bf2f(short s){
  union { uint32_t u; float f; } v; v.u = ((uint32_t)(uint16_t)s) << 16;
  return v.f;
}
__device__ __forceinline__ float sigmoidf_(float x){ return 1.f/(1.f+__expf(-x)); }

// LDS-only barrier: waits lgkmcnt(0) but leaves vmcnt (global prefetch) in flight.
__device__ __forceinline__ void lds_barrier(){
  asm volatile("s_waitcnt lgkmcnt(0)\n\ts_barrier" ::: "memory");
}

// ---------------- prep: x stats partials (1024 blks) + bf16 weight conversion ----------------
__global__ __launch_bounds__(256) void k_prep(
    const float* __restrict__ x,
    const float* __restrict__ w1, const float* __restrict__ w2,
    const float* __restrict__ w3, const float* __restrict__ w4,
    float* __restrict__ xstat, short* __restrict__ wbf)
{
  int blk = blockIdx.x, tid = threadIdx.x;
  if (blk < 1024) {
    int b = blk >> 8, chunk = blk & 255;
    const float* base = x + (size_t)b*CH*NP + (size_t)chunk*16384;
    float s = 0.f, s2 = 0.f;
    for (int i = tid*4; i < 16384; i += 1024) {
      f32x4 v = *(const f32x4*)(base + i);
      s  += v.x + v.y + v.z + v.w;
      s2 += v.x*v.x + v.y*v.y + v.z*v.z + v.w*v.w;
    }
    for (int d=1; d<64; d<<=1){ s += __shfl_xor(s,d,64); s2 += __shfl_xor(s2,d,64); }
    __shared__ float ls[8];
    int wv = tid>>6;
    if ((tid&63)==0){ ls[wv]=s; ls[4+wv]=s2; }
    __syncthreads();
    if (tid==0){
      xstat[blk*2]   = ls[0]+ls[1]+ls[2]+ls[3];
      xstat[blk*2+1] = ls[4]+ls[5]+ls[6]+ls[7];
    }
  } else {
    int wblk = blk - 1024;  // 24 blocks x 1024 elems
    const float* src; short* dst; int off;
    if (wblk < 8)       { src = w1; dst = wbf;         off = wblk*1024; }
    else if (wblk < 12) { src = w2; dst = wbf + 8192;  off = (wblk-8)*1024; }
    else if (wblk < 20) { src = w3; dst = wbf + 12288; off = (wblk-12)*1024; }
    else                { src = w4; dst = wbf + 20480; off = (wblk-20)*1024; }
    for (int i = tid; i < 1024; i += 256) dst[off+i] = f2bf(src[off+i]);
  }
}

__global__ void k_fin1(const float* __restrict__ xstat, float* __restrict__ stats1){
  int b = threadIdx.x >> 6, lane = threadIdx.x & 63;
  float s=0.f, s2=0.f;
  #pragma unroll
  for (int j=0;j<4;j++){
    int i = b*256 + j*64 + lane;
    s += xstat[i*2]; s2 += xstat[i*2+1];
  }
  for (int d=1; d<64; d<<=1){ s += __shfl_xor(s,d,64); s2 += __shfl_xor(s2,d,64); }
  if (lane==0){
    float m = s*(1.f/4194304.f);
    float v = s2*(1.f/4194304.f) - m*m;
    stats1[b]=m; stats1[4+b]=rsqrtf(v+EPS_LN);
  }
}

// ---------------- branch1: LN1 + GEMM w1(*dww folded) + GLU -> hglu[pos][c] + pool partial ----------------
__global__ __launch_bounds__(256,4) void k_branch1(
    const float* __restrict__ x, const float* __restrict__ lnw, const float* __restrict__ lnb,
    const short* __restrict__ w1bf, const float* __restrict__ b1,
    const float* __restrict__ dww, const float* __restrict__ dwb,
    const float* __restrict__ stats1, short* __restrict__ hglu, float* __restrict__ ppart)
{
  int blk = blockIdx.x;                 // 1024
  int b = blk >> 8;
  int tile0 = (blk & 255) * 4;
  int tid = threadIdx.x, wv = tid>>6, lane = tid&63, l = lane&15, q = lane>>4;
  int c_ = tid>>4, p4 = tid&15;
  float mean = stats1[b], rstd = stats1[4+b];
  const float* xb = x + (size_t)b*CH*NP;
  short* hb = hglu + (size_t)b*CH*NP;   // [pos][c]

  __shared__ __align__(16) short wlds[8192];   // w1*dww, fragment-linear
  __shared__ __align__(16) short lin[64*78];   // LN'd bf16, [c][pos] stride 78
  __shared__ float pacc[4][64];
  __shared__ __align__(16) float cc[128];      // b1*dww + dwb

  // stage weights (fragment order: g = mt*128 + ks*64 + q*16 + l, 8 elems each)
  #pragma unroll
  for (int g0=0; g0<4; g0++){
    int g = g0*256 + tid;
    int mt = g>>7, ks = (g>>6)&1, qq = (g>>4)&3, ll = g&15;
    int m = mt*16 + ll;
    float sc = dww[m];
    bf16x8 w8 = *(const bf16x8*)(w1bf + (m*CH + ks*32 + qq*8));
    #pragma unroll
    for (int j=0;j<8;j++) w8[j] = f2bf(bf2f(w8[j]) * sc);
    *(bf16x8*)(&wlds[g*8]) = w8;
  }
  if (tid < 128) cc[tid] = b1[tid]*dww[tid] + dwb[tid];
  // first use of wlds/cc is after barrier A of tile 0

  // initial prefetch (tile 0)
  f32x4 pX[4], pW[4], pB[4];
  #pragma unroll
  for (int it=0; it<4; it++){
    int c = it*16 + c_;
    size_t o = (size_t)c*NP + tile0*64 + p4*4;
    pX[it] = *(const f32x4*)(xb + o);
    pW[it] = *(const f32x4*)(lnw + o);
    pB[it] = *(const f32x4*)(lnb + o);
  }

  float rsum[16];
  #pragma unroll
  for (int i=0;i<16;i++) rsum[i] = 0.f;

  for (int t=0; t<4; t++){
    int pos0 = (tile0 + t)*64;
    // stage-in: LN -> lin
    #pragma unroll
    for (int it=0; it<4; it++){
      int c = it*16 + c_;
      s16x2 lo, hi;
      lo[0] = f2bf((pX[it][0]-mean)*rstd*pW[it][0] + pB[it][0]);
      lo[1] = f2bf((pX[it][1]-mean)*rstd*pW[it][1] + pB[it][1]);
      hi[0] = f2bf((pX[it][2]-mean)*rstd*pW[it][2] + pB[it][2]);
      hi[1] = f2bf((pX[it][3]-mean)*rstd*pW[it][3] + pB[it][3]);
      *(s16x2*)(&lin[c*78 + p4*4])     = lo;
      *(s16x2*)(&lin[c*78 + p4*4 + 2]) = hi;
    }
    // prefetch next tile (in flight across the barriers below)
    if (t < 3){
      #pragma unroll
      for (int it=0; it<4; it++){
        int c = it*16 + c_;
        size_t o = (size_t)c*NP + pos0 + 64 + p4*4;
        pX[it] = *(const f32x4*)(xb + o);
        pW[it] = *(const f32x4*)(lnw + o);
        pB[it] = *(const f32x4*)(lnb + o);
      }
    }
    lds_barrier();   // A: lin (and, at t=0, wlds/cc) visible

    bf16x8 bfrag[2];
    #pragma unroll
    for (int ks=0; ks<2; ks++)
      #pragma unroll
      for (int j=0; j<8; j++)
        bfrag[ks][j] = lin[(ks*32+q*8+j)*78 + wv*16 + l];

    f32x4 acc[8];
    #pragma unroll
    for (int mt=0; mt<8; mt++){
      f32x4 a = {0.f,0.f,0.f,0.f};
      #pragma unroll
      for (int ks=0; ks<2; ks++){
        bf16x8 af = *(const bf16x8*)(&wlds[(mt*128 + ks*64 + q*16 + l)*8]);
        a = __builtin_amdgcn_mfma_f32_16x16x32_bf16(af, bfrag[ks], a, 0, 0, 0);
      }
      acc[mt] = a;
    }

    int pos = pos0 + wv*16 + l;
    #pragma unroll
    for (int mt=0; mt<4; mt++){
      f32x4 ccA = *(const f32x4*)(&cc[mt*16 + q*4]);
      f32x4 ccG = *(const f32x4*)(&cc[64 + mt*16 + q*4]);
      s16x4 pk;
      #pragma unroll
      for (int r=0; r<4; r++){
        float av = acc[mt][r]   + ccA[r];
        float gv = acc[mt+4][r] + ccG[r];
        float h = av * sigmoidf_(gv);
        rsum[mt*4+r] += h;
        pk[r] = f2bf(h);
      }
      *(s16x4*)(hb + (size_t)pos*CH + mt*16 + q*4) = pk;
    }
    lds_barrier();   // B: bfrag reads done (lin reusable next tile)
  }

  // pool partial: reduce rsum over the 16 lanes (l) of each quad, then across waves
  #pragma unroll
  for (int i=0;i<16;i++){
    float v = rsum[i];
    v += __shfl_xor(v,1,64); v += __shfl_xor(v,2,64);
    v += __shfl_xor(v,4,64); v += __shfl_xor(v,8,64);
    if (l==0) pacc[wv][(i>>2)*16 + q*4 + (i&3)] = v;
  }
  lds_barrier();
  if (tid < 64){
    float s = pacc[0][tid]+pacc[1][tid]+pacc[2][tid]+pacc[3][tid];
    ppart[((size_t)b*256 + (blk & 255))*64 + tid] = s;
  }
}

// ---------------- channel attention MLP + fold s into w2 -> w2s[b] (bf16) ----------------
// ppart is pre-reduced: [4][256][64]. 1024 threads/block, 1 block/batch.
__global__ __launch_bounds__(1024) void k_attn(
    const float* __restrict__ ppart,
    const float* __restrict__ aw1, const float* __restrict__ ab1,
    const float* __restrict__ aw2, const float* __restrict__ ab2,
    const short* __restrict__ w2bf, short* __restrict__ w2s)
{
  int b = blockIdx.x, t = threadIdx.x;
  int c = t & 63, seg = t >> 6;        // seg 0..15
  __shared__ float awl1[64*65], awl2[64*65];   // row-padded to 65: conflict-free
  __shared__ float pl[16][64];
  __shared__ float parr[64], t1a[64], sarr[64];

  // stage MLP weights to LDS (conflict-free: consecutive addrs per wave)
  #pragma unroll
  for (int k=0;k<4;k++){
    int i = t + k*1024;
    int row = i >> 6, col = i & 63;
    awl1[row*65 + col] = aw1[i];
    awl2[row*65 + col] = aw2[i];
  }
  // pooling: 16 coalesced loads per thread
  const float* pb = ppart + (size_t)b*256*64;
  float s = 0.f;
  #pragma unroll
  for (int k=0;k<16;k++) s += pb[(seg*16 + k)*64 + c];
  pl[seg][c] = s;
  __syncthreads();
  if (t < 64){
    float acc = 0.f;
    #pragma unroll
    for (int j=0;j<16;j++) acc += pl[j][t];
    parr[t] = acc * (1.f/65536.f);
  }
  __syncthreads();
  if (t < 64){
    float acc = ab1[t];
    #pragma unroll
    for (int k=0;k<64;k++) acc += awl1[t*65+k]*parr[k];
    t1a[t] = fmaxf(acc, 0.f);
  }
  __syncthreads();
  if (t < 64){
    float acc = ab2[t];
    #pragma unroll
    for (int k=0;k<64;k++) acc += awl2[t*65+k]*t1a[k];
    sarr[t] = sigmoidf_(acc);
  }
  __syncthreads();
  #pragma unroll
  for (int k=0;k<4;k++){
    int i = t + k*1024;
    w2s[b*4096 + i] = f2bf(bf2f(w2bf[i]) * sarr[i & 63]);
  }
}

// ---------------- mid: GEMM w2s + b2 + x -> y (d_out) + y stats partials ----------------
__global__ __launch_bounds__(256,4) void k_mid(
    const short* __restrict__ hglu, const short* __restrict__ w2s,
    const float* __restrict__ b2, const float* __restrict__ x,
    float* __restrict__ y, float* __restrict__ ystat)
{
  int blk = blockIdx.x;                 // 1024
  int b = blk >> 8;
  int tile0 = (blk & 255) * 4;
  int tid = threadIdx.x, wv = tid>>6, lane = tid&63, l = lane&15, q = lane>>4;
  int c_ = tid>>4, p4 = tid&15;
  const short* hb = hglu + (size_t)b*CH*NP;
  const float* xb = x + (size_t)b*CH*NP;
  float* yb = y + (size_t)b*CH*NP;
  int posl = wv*16 + l;

  __shared__ __align__(16) short w2l[4096];
  __shared__ __align__(16) float lout[64*65];

  #pragma unroll
  for (int g0=0; g0<2; g0++){
    int g = g0*256 + tid;
    int mt = g>>7, ks = (g>>6)&1, qq = (g>>4)&3, ll = g&15;
    *(bf16x8*)(&w2l[g*8]) = *(const bf16x8*)(w2s + b*4096 + (mt*16+ll)*CH + ks*32 + qq*8);
  }
  float b2v[4];
  #pragma unroll
  for (int it=0; it<4; it++) b2v[it] = b2[it*16 + c_];

  // initial prefetch (issued before the staging barrier so loads are in flight)
  bf16x8 pH0, pH1; f32x4 pXr[4];
  {
    const short* hr = hb + (size_t)(tile0*64 + posl)*CH;
    pH0 = *(const bf16x8*)(hr + q*8);
    pH1 = *(const bf16x8*)(hr + 32 + q*8);
    #pragma unroll
    for (int it=0; it<4; it++)
      pXr[it] = *(const f32x4*)(xb + (size_t)(it*16+c_)*NP + tile0*64 + p4*4);
  }
  lds_barrier();   // S: w2l staged by ALL threads visible before first MFMA

  float s1 = 0.f, s2 = 0.f;

  for (int t=0; t<4; t++){
    int pos0 = (tile0 + t)*64;
    bf16x8 h0 = pH0, h1 = pH1;
    if (t < 3){
      const short* hr = hb + (size_t)(pos0 + 64 + posl)*CH;
      pH0 = *(const bf16x8*)(hr + q*8);
      pH1 = *(const bf16x8*)(hr + 32 + q*8);
    }
    f32x4 acc[4];
    #pragma unroll
    for (int mt=0; mt<4; mt++){
      f32x4 a = {0.f,0.f,0.f,0.f};
      a = __builtin_amdgcn_mfma_f32_16x16x32_bf16(
            *(const bf16x8*)(&w2l[(mt*128 + 0*64 + q*16 + l)*8]), h0, a, 0,0,0);
      a = __builtin_amdgcn_mfma_f32_16x16x32_bf16(
            *(const bf16x8*)(&w2l[(mt*128 + 1*64 + q*16 + l)*8]), h1, a, 0,0,0);
      acc[mt] = a;
    }
    #pragma unroll
    for (int mt=0; mt<4; mt++)
      #pragma unroll
      for (int r=0; r<4; r++)
        lout[posl*65 + mt*16 + q*4 + r] = acc[mt][r];
    lds_barrier();   // B1: lout visible

    f32x4 yv[4];
    #pragma unroll
    for (int it=0; it<4; it++){
      int c = it*16 + c_;
      #pragma unroll
      for (int j=0; j<4; j++){
        float v = lout[(p4*4+j)*65 + c] + b2v[it] + pXr[it][j];
        yv[it][j] = v; s1 += v; s2 += v*v;
      }
    }
    if (t < 3){
      #pragma unroll
      for (int it=0; it<4; it++)
        pXr[it] = *(const f32x4*)(xb + (size_t)(it*16+c_)*NP + pos0 + 64 + p4*4);
    }
    #pragma unroll
    for (int it=0; it<4; it++)
      *(f32x4*)(yb + (size_t)(it*16+c_)*NP + pos0 + p4*4) = yv[it];
    lds_barrier();   // B2: lout reads done before next tile's writes
  }

  for (int d=1; d<64; d<<=1){ s1 += __shfl_xor(s1,d,64); s2 += __shfl_xor(s2,d,64); }
  __shared__ float red[8];
  if (lane==0){ red[wv]=s1; red[4+wv]=s2; }
  __syncthreads();
  if (tid==0){
    ystat[(size_t)blk*2]   = red[0]+red[1]+red[2]+red[3];
    ystat[(size_t)blk*2+1] = red[4]+red[5]+red[6]+red[7];
  }
}

__global__ void k_fin2(const float* __restrict__ ystat, float* __restrict__ stats2){
  int t = threadIdx.x;           // 256
  int b = t >> 6, lane = t & 63;
  float s=0.f, s2=0.f;
  #pragma unroll
  for (int j=0;j<4;j++){
    int e = b*256 + j*64 + lane;
    s  += ystat[e*2];
    s2 += ystat[e*2+1];
  }
  for (int d=1; d<64; d<<=1){ s += __shfl_xor(s,d,64); s2 += __shfl_xor(s2,d,64); }
  if (lane==0){
    float m = s*(1.f/4194304.f);
    float v = s2*(1.f/4194304.f) - m*m;
    stats2[b]=m; stats2[4+b]=rsqrtf(v+EPS_LN);
  }
}

// ---------------- branch2: LN2 + GEMM w3 + GLU + GEMM w4 + residual (in-place over y) ----------------
__global__ __launch_bounds__(256,3) void k_branch2(
    float* __restrict__ yio, const float* __restrict__ lnw, const float* __restrict__ lnb,
    const short* __restrict__ w3bf, const float* __restrict__ b3,
    const short* __restrict__ w4bf, const float* __restrict__ b4,
    const float* __restrict__ stats2)
{
  int blk = blockIdx.x;                 // 1024
  int b = blk >> 8;
  int tile0 = (blk & 255) * 4;
  int tid = threadIdx.x, wv = tid>>6, lane = tid&63, l = lane&15, q = lane>>4;
  int c_ = tid>>4, p4 = tid&15;
  float mean = stats2[b], rstd = stats2[4+b];
  float* yb = yio + (size_t)b*CH*NP;
  int posl = wv*16 + l;

  __shared__ __align__(16) short w3l[8192];
  __shared__ __align__(16) short w4l[4096];
  __shared__ __align__(16) short lin[64*78];
  __shared__ __align__(16) char lun[64*65*4];   // lglu (short, stride 72) ∪ lout (float, stride 65)
  short* lglu = (short*)lun;
  float* lout = (float*)lun;
  __shared__ __align__(16) float b3l[128];

  #pragma unroll
  for (int g0=0; g0<4; g0++){
    int g = g0*256 + tid;
    int mt = g>>7, ks = (g>>6)&1, qq = (g>>4)&3, ll = g&15;
    *(bf16x8*)(&w3l[g*8]) = *(const bf16x8*)(w3bf + ((mt*16+ll)*CH + ks*32 + qq*8));
  }
  #pragma unroll
  for (int g0=0; g0<2; g0++){
    int g = g0*256 + tid;
    int mt = g>>7, ks = (g>>6)&1, qq = (g>>4)&3, ll = g&15;
    *(bf16x8*)(&w4l[g*8]) = *(const bf16x8*)(w4bf + ((mt*16+ll)*CH + ks*32 + qq*8));
  }
  if (tid < 128) b3l[tid] = b3[tid];
  float b4v[4];
  #pragma unroll
  for (int it=0; it<4; it++) b4v[it] = b4[it*16 + c_];
  // first use of w3l/b3l is after barrier A; w4l after barrier C — covered

  // initial prefetch
  f32x4 pY[4], pW[4], pB[4];
  #pragma unroll
  for (int it=0; it<4; it++){
    int c = it*16 + c_;
    size_t o = (size_t)c*NP + tile0*64 + p4*4;
    pY[it] = *(const f32x4*)(yb + o);
    pW[it] = *(const f32x4*)(lnw + o);
    pB[it] = *(const f32x4*)(lnb + o);
  }

  for (int t=0; t<4; t++){
    int pos0 = (tile0 + t)*64;
    // stage-in: LN -> lin   (pY kept for residual)
    #pragma unroll
    for (int it=0; it<4; it++){
      int c = it*16 + c_;
      s16x2 lo, hi;
      lo[0] = f2bf((pY[it][0]-mean)*rstd*pW[it][0] + pB[it][0]);
      lo[1] = f2bf((pY[it][1]-mean)*rstd*pW[it][1] + pB[it][1]);
      hi[0] = f2bf((pY[it][2]-mean)*rstd*pW[it][2] + pB[it][2]);
      hi[1] = f2bf((pY[it][3]-mean)*rstd*pW[it][3] + pB[it][3]);
      *(s16x2*)(&lin[c*78 + p4*4])     = lo;
      *(s16x2*)(&lin[c*78 + p4*4 + 2]) = hi;
    }
    if (t < 3){
      #pragma unroll
      for (int it=0; it<4; it++){
        int c = it*16 + c_;
        size_t o = (size_t)c*NP + pos0 + 64 + p4*4;
        pW[it] = *(const f32x4*)(lnw + o);
        pB[it] = *(const f32x4*)(lnb + o);
      }
    }
    lds_barrier();   // A: lin visible (also covers w3l/b3l at t=0; prior-tile lout reads done)

    bf16x8 bfrag[2];
    #pragma unroll
    for (int ks=0; ks<2; ks++)
      #pragma unroll
      for (int j=0; j<8; j++)
        bfrag[ks][j] = lin[(ks*32+q*8+j)*78 + wv*16 + l];

    f32x4 acc[8];
    #pragma unroll
    for (int mt=0; mt<8; mt++){
      f32x4 a = {0.f,0.f,0.f,0.f};
      #pragma unroll
      for (int ks=0; ks<2; ks++){
        bf16x8 af = *(const bf16x8*)(&w3l[(mt*128 + ks*64 + q*16 + l)*8]);
        a = __builtin_amdgcn_mfma_f32_16x16x32_bf16(af, bfrag[ks], a, 0, 0, 0);
      }
      acc[mt] = a;
    }

    // GLU -> lglu
    #pragma unroll
    for (int mt=0; mt<4; mt++){
      f32x4 bA = *(const f32x4*)(&b3l[mt*16 + q*4]);
      f32x4 bG = *(const f32x4*)(&b3l[64 + mt*16 + q*4]);
      s16x4 pk;
      #pragma unroll
      for (int r=0; r<4; r++){
        float av = acc[mt][r]   + bA[r];
        float gv = acc[mt+4][r] + bG[r];
        pk[r] = f2bf(av * sigmoidf_(gv));
      }
      *(s16x4*)(&lglu[posl*72 + mt*16 + q*4]) = pk;
    }
    lds_barrier();   // C: lglu visible (also covers w4l at t=0)

    bf16x8 pfrag[2];
    pfrag[0] = *(const bf16x8*)(&lglu[posl*72 + q*8]);
    pfrag[1] = *(const bf16x8*)(&lglu[posl*72 + 32 + q*8]);
    lds_barrier();   // C2: pfrag reads done before lout overwrites the union

    f32x4 acc2[4];
    #pragma unroll
    for (int mt=0; mt<4; mt++){
      f32x4 a = {0.f,0.f,0.f,0.f};
      #pragma unroll
      for (int ks=0; ks<2; ks++){
        bf16x8 af = *(const bf16x8*)(&w4l[(mt*128 + ks*64 + q*16 + l)*8]);
        a = __builtin_amdgcn_mfma_f32_16x16x32_bf16(af, ks ? pfrag[1] : pfrag[0], a, 0, 0, 0);
      }
      acc2[mt] = a;
    }
    #pragma unroll
    for (int mt=0; mt<4; mt++)
      #pragma unroll
      for (int r=0; r<4; r++)
        lout[posl*65 + mt*16 + q*4 + r] = acc2[mt][r];
    lds_barrier();   // D: lout visible

    f32x4 yv[4];
    #pragma unroll
    for (int it=0; it<4; it++){
      int c = it*16 + c_;
      #pragma unroll
      for (int j=0; j<4; j++)
        yv[it][j] = lout[(p4*4+j)*65 + c] + b4v[it] + pY[it][j];
    }
    if (t < 3){
      #pragma unroll
      for (int it=0; it<4; it++){
        int c = it*16 + c_;
        pY[it] = *(const f32x4*)(yb + (size_t)c*NP + pos0 + 64 + p4*4);
      }
    }
    #pragma unroll
    for (int it=0; it<4; it++)
      *(f32x4*)(yb + (size_t)(it*16+c_)*NP + pos0 + p4*4) = yv[it];
  }
}

extern "C" void kernel_launch(void* const* d_in, const int* in_sizes, int n_in,
                              void* d_out, int out_size, void* d_ws, size_t ws_size,
                              hipStream_t stream){
  const float* x    = (const float*)d_in[0];
  const float* ln1w = (const float*)d_in[1];
  const float* ln1b = (const float*)d_in[2];
  const float* ln2w = (const float*)d_in[3];
  const float* ln2b = (const float*)d_in[4];
  const float* w1   = (const float*)d_in[5];
  const float* b1   = (const float*)d_in[6];
  const float* dww  = (const float*)d_in[7];
  const float* dwb  = (const float*)d_in[8];
  const float* aw1  = (const float*)d_in[9];
  const float* ab1  = (const float*)d_in[10];
  const float* aw2  = (const float*)d_in[11];
  const float* ab2  = (const float*)d_in[12];
  const float* w2   = (const float*)d_in[13];
  const float* b2   = (const float*)d_in[14];
  const float* w3   = (const float*)d_in[15];
  const float* b3   = (const float*)d_in[16];
  const float* w4   = (const float*)d_in[17];
  const float* b4   = (const float*)d_in[18];
  float* out = (float*)d_out;
  float* ws  = (float*)d_ws;

  // ws layout (float offsets)
  float* xstat  = ws;                     // 2048
  float* stats1 = ws + 2048;              // 8
  float* ystat  = ws + 2112;              // 2048
  float* stats2 = ws + 10304;             // 8
  short* wbf    = (short*)(ws + 10368);   // 24576 bf16: w1|w2|w3|w4
  short* w2s    = (short*)(ws + 22656);   // 16384 bf16: per-batch scaled w2
  float* ppart  = ws + 30848;             // 65536 (pre-reduced [4][256][64])
  short* hglu   = (short*)(ws + 292992);  // 16777216 bf16 [b][pos][c]; total ~34.7 MB

  hipLaunchKernelGGL(k_prep,    dim3(1048), dim3(256),  0, stream, x, w1, w2, w3, w4, xstat, wbf);
  hipLaunchKernelGGL(k_fin1,    dim3(1),    dim3(256),  0, stream, xstat, stats1);
  hipLaunchKernelGGL(k_branch1, dim3(1024), dim3(256),  0, stream, x, ln1w, ln1b, wbf, b1, dww, dwb, stats1, hglu, ppart);
  hipLaunchKernelGGL(k_attn,    dim3(4),    dim3(1024), 0, stream, ppart, aw1, ab1, aw2, ab2, wbf + 8192, w2s);
  hipLaunchKernelGGL(k_mid,     dim3(1024), dim3(256),  0, stream, hglu, w2s, b2, x, out, ystat);
  hipLaunchKernelGGL(k_fin2,    dim3(1),    dim3(256),  0, stream, ystat, stats2);
  hipLaunchKernelGGL(k_branch2, dim3(1024), dim3(256),  0, stream, out, ln2w, ln2b, wbf + 12288, b3, wbf + 20480, b4, stats2);
}